// Round 1
// baseline (198.144 us; speedup 1.0000x reference)
//
#include <hip/hip_runtime.h>
#include <cmath>

constexpr int B_ = 16, N_ = 10, H_ = 400, W_ = 400;
constexpr int HW = H_ * W_;              // 160000
constexpr int BN = B_ * N_;              // 160
constexpr int SPLITS = 16;               // blocks per (b,n) image
constexpr int CHUNK4 = HW / 4 / SPLITS;  // 2500 float4s per block

// ws layout: [0, BN)        overlap accumulators
//            [BN, BN + B_)  tgt_area accumulators
__global__ void zero_ws(float* ws) {
    int i = blockIdx.x * blockDim.x + threadIdx.x;
    if (i < BN + B_) ws[i] = 0.0f;
}

__device__ __forceinline__ float block_reduce_sum(float v, float* sm) {
#pragma unroll
    for (int off = 32; off > 0; off >>= 1) v += __shfl_down(v, off, 64);
    int lane = threadIdx.x & 63;
    int wid  = threadIdx.x >> 6;
    if (lane == 0) sm[wid] = v;
    __syncthreads();
    float r = 0.0f;
    if (threadIdx.x == 0) r = sm[0] + sm[1] + sm[2] + sm[3];
    return r;  // valid on thread 0 only
}

__global__ void __launch_bounds__(256)
overlap_k(const float4* __restrict__ om, const float4* __restrict__ tm,
          float* __restrict__ ws) {
    __shared__ float sm[4];
    __shared__ float sm2[4];
    int bn = blockIdx.x / SPLITS;
    int s  = blockIdx.x % SPLITS;
    int b  = bn / N_;
    int n  = bn % N_;
    const float4* omp = om + (size_t)bn * (HW / 4) + (size_t)s * CHUNK4;
    const float4* tmp = tm + (size_t)b  * (HW / 4) + (size_t)s * CHUNK4;
    float acc = 0.0f, tacc = 0.0f;
    for (int i = threadIdx.x; i < CHUNK4; i += 256) {
        float4 o = omp[i];
        float4 t = tmp[i];
        acc  += o.x * t.x + o.y * t.y + o.z * t.z + o.w * t.w;
        tacc += t.x + t.y + t.z + t.w;
    }
    float bacc = block_reduce_sum(acc, sm);
    if (threadIdx.x == 0) atomicAdd(&ws[bn], bacc);
    if (n == 0) {  // uniform across block — safe with __syncthreads inside
        float btacc = block_reduce_sum(tacc, sm2);
        if (threadIdx.x == 0) atomicAdd(&ws[BN + b], btacc);
    }
}

__global__ void __launch_bounds__(256)
finalize_k(const float* __restrict__ bboxes, const float* __restrict__ tm,
           const float* __restrict__ ws, float* __restrict__ out) {
    __shared__ float sm[4];
    int bn = blockIdx.x;
    int b  = bn / N_;
    float4 bb = reinterpret_cast<const float4*>(bboxes)[bn];
    int x1 = (int)floorf(bb.x), y1 = (int)floorf(bb.y);
    int x2 = (int)floorf(bb.z), y2 = (int)floorf(bb.w);
    // counts of integer grid points in [0,H)x[0,W) inside the box
    int ry1 = max(y1, 0), ry2 = min(y2, H_);
    int rx1 = max(x1, 0), rx2 = min(x2, W_);
    float inter = 0.0f;
    for (int r = ry1; r < ry2; ++r) {
        const float* row = tm + ((size_t)b * H_ + r) * W_;
        for (int c = rx1 + (int)threadIdx.x; c < rx2; c += 256) inter += row[c];
    }
    float itot = block_reduce_sum(inter, sm);
    if (threadIdx.x == 0) {
        float cr = (float)max(0, ry2 - ry1);
        float cc = (float)max(0, rx2 - rx1);
        float box_area = cr * cc;
        float ov  = ws[bn];
        float tgt = ws[BN + b];
        float iou = itot / (box_area + tgt - itot + 1e-8f);
        out[bn * 2 + 0] = ov;
        out[bn * 2 + 1] = iou;
    }
}

extern "C" void kernel_launch(void* const* d_in, const int* in_sizes, int n_in,
                              void* d_out, int out_size, void* d_ws, size_t ws_size,
                              hipStream_t stream) {
    const float*  bboxes = (const float*)d_in[0];
    const float4* om     = (const float4*)d_in[1];
    const float4* tm4    = (const float4*)d_in[2];
    const float*  tm     = (const float*)d_in[2];
    float* out = (float*)d_out;
    float* ws  = (float*)d_ws;

    zero_ws<<<1, 256, 0, stream>>>(ws);
    overlap_k<<<BN * SPLITS, 256, 0, stream>>>(om, tm4, ws);
    finalize_k<<<BN, 256, 0, stream>>>(bboxes, tm, ws, out);
}

// Round 2
// 47.014 us; speedup vs baseline: 4.2146x; 4.2146x over previous
//
#include <hip/hip_runtime.h>
#include <cmath>

constexpr int B_ = 16, N_ = 10, H_ = 400, W_ = 400;
constexpr int HW = H_ * W_;              // 160000
constexpr int BN = B_ * N_;              // 160
constexpr int SPLITS = 16;               // blocks per (b,n) image for overlap
constexpr int CHUNK4 = HW / 4 / SPLITS;  // 2500 float4s per block
constexpr int ISPLITS = 16;              // blocks per (b,n) for inter

// ws layout: [0, BN)            overlap accumulators
//            [BN, BN+B_)        tgt_area accumulators
//            [BN+B_, 2*BN+B_)   inter accumulators
constexpr int OFF_TGT   = BN;
constexpr int OFF_INTER = BN + B_;
constexpr int WS_N      = 2 * BN + B_;

__global__ void zero_ws(float* ws) {
    int i = blockIdx.x * blockDim.x + threadIdx.x;
    if (i < WS_N) ws[i] = 0.0f;
}

__device__ __forceinline__ float block_reduce_sum(float v, float* sm) {
#pragma unroll
    for (int off = 32; off > 0; off >>= 1) v += __shfl_down(v, off, 64);
    int lane = threadIdx.x & 63;
    int wid  = threadIdx.x >> 6;
    if (lane == 0) sm[wid] = v;
    __syncthreads();
    float r = 0.0f;
    if (threadIdx.x == 0) r = sm[0] + sm[1] + sm[2] + sm[3];
    return r;  // valid on thread 0 only
}

__global__ void __launch_bounds__(256)
overlap_k(const float4* __restrict__ om, const float4* __restrict__ tm,
          float* __restrict__ ws) {
    __shared__ float sm[4];
    __shared__ float sm2[4];
    int bn = blockIdx.x / SPLITS;
    int s  = blockIdx.x % SPLITS;
    int b  = bn / N_;
    int n  = bn % N_;
    const float4* omp = om + (size_t)bn * (HW / 4) + (size_t)s * CHUNK4;
    const float4* tmp = tm + (size_t)b  * (HW / 4) + (size_t)s * CHUNK4;
    float acc = 0.0f, tacc = 0.0f;
    for (int i = threadIdx.x; i < CHUNK4; i += 256) {
        float4 o = omp[i];
        float4 t = tmp[i];
        acc  += o.x * t.x + o.y * t.y + o.z * t.z + o.w * t.w;
        tacc += t.x + t.y + t.z + t.w;
    }
    float bacc = block_reduce_sum(acc, sm);
    if (threadIdx.x == 0) atomicAdd(&ws[bn], bacc);
    if (n == 0) {  // uniform across block — safe with __syncthreads inside
        float btacc = block_reduce_sum(tacc, sm2);
        if (threadIdx.x == 0) atomicAdd(&ws[OFF_TGT + b], btacc);
    }
}

// Region sum of tm over the (clipped, integer) bbox. Rows of each box are
// split across ISPLITS blocks; within a block the (rows x cols) slab is
// flattened so all 256 lanes issue independent loads every iteration.
__global__ void __launch_bounds__(256)
inter_k(const float* __restrict__ bboxes, const float* __restrict__ tm,
        float* __restrict__ ws) {
    __shared__ float sm[4];
    int bn = blockIdx.x / ISPLITS;
    int s  = blockIdx.x % ISPLITS;
    int b  = bn / N_;
    float4 bb = reinterpret_cast<const float4*>(bboxes)[bn];
    int x1 = (int)floorf(bb.x), y1 = (int)floorf(bb.y);
    int x2 = (int)floorf(bb.z), y2 = (int)floorf(bb.w);
    int ry1 = max(y1, 0), ry2 = min(y2, H_);
    int rx1 = max(x1, 0), rx2 = min(x2, W_);
    int rows = ry2 - ry1, cols = rx2 - rx1;
    if (rows <= 0 || cols <= 0) return;            // uniform per block
    int stripe = (rows + ISPLITS - 1) / ISPLITS;
    int r0 = ry1 + s * stripe;
    int r1 = min(r0 + stripe, ry2);
    int nrows = r1 - r0;
    if (nrows <= 0) return;                        // uniform per block
    int total = nrows * cols;
    const float* base = tm + (size_t)b * HW;
    float acc = 0.0f;
    for (int i = threadIdx.x; i < total; i += 256) {
        int r = r0 + i / cols;
        int c = rx1 + i % cols;
        acc += base[r * W_ + c];
    }
    float bacc = block_reduce_sum(acc, sm);
    if (threadIdx.x == 0) atomicAdd(&ws[OFF_INTER + bn], bacc);
}

__global__ void __launch_bounds__(256)
finalize2_k(const float* __restrict__ bboxes, const float* __restrict__ ws,
            float* __restrict__ out) {
    int bn = threadIdx.x;
    if (bn >= BN) return;
    float4 bb = reinterpret_cast<const float4*>(bboxes)[bn];
    int x1 = (int)floorf(bb.x), y1 = (int)floorf(bb.y);
    int x2 = (int)floorf(bb.z), y2 = (int)floorf(bb.w);
    int ry1 = max(y1, 0), ry2 = min(y2, H_);
    int rx1 = max(x1, 0), rx2 = min(x2, W_);
    float cr = (float)max(0, ry2 - ry1);
    float cc = (float)max(0, rx2 - rx1);
    float box_area = cr * cc;
    int b = bn / N_;
    float ov    = ws[bn];
    float tgt   = ws[OFF_TGT + b];
    float inter = ws[OFF_INTER + bn];
    float iou = inter / (box_area + tgt - inter + 1e-8f);
    out[bn * 2 + 0] = ov;
    out[bn * 2 + 1] = iou;
}

extern "C" void kernel_launch(void* const* d_in, const int* in_sizes, int n_in,
                              void* d_out, int out_size, void* d_ws, size_t ws_size,
                              hipStream_t stream) {
    const float*  bboxes = (const float*)d_in[0];
    const float4* om     = (const float4*)d_in[1];
    const float4* tm4    = (const float4*)d_in[2];
    const float*  tm     = (const float*)d_in[2];
    float* out = (float*)d_out;
    float* ws  = (float*)d_ws;

    zero_ws<<<1, 384, 0, stream>>>(ws);
    overlap_k<<<BN * SPLITS, 256, 0, stream>>>(om, tm4, ws);
    inter_k<<<BN * ISPLITS, 256, 0, stream>>>(bboxes, tm, ws);
    finalize2_k<<<1, 256, 0, stream>>>(bboxes, ws, out);
}

// Round 3
// 25.262 us; speedup vs baseline: 7.8436x; 1.8611x over previous
//
#include <hip/hip_runtime.h>
#include <cmath>

constexpr int B_ = 16, N_ = 10, H_ = 400, W_ = 400;
constexpr int HW = H_ * W_;              // 160000
constexpr int BN = B_ * N_;              // 160
constexpr int SPLITS = 16;               // blocks per (b,n) image
constexpr int CHUNK4 = HW / 4 / SPLITS;  // 2500 float4s per block

// ws layout (all partials; every slot written every call -> no zeroing):
//   [0, BN*SPLITS)                overlap partials, slot = blockIdx
//   [BN*SPLITS, 2*BN*SPLITS)      inter partials,   slot = OFF_I + blockIdx
//   [2*BN*SPLITS, +B_*SPLITS)     tgt_area partials (from n==0 blocks)
constexpr int OFF_I = BN * SPLITS;
constexpr int OFF_T = 2 * BN * SPLITS;

// Fused: per (b,n,stripe) block computes partial overlap (om.tm dot),
// partial inter (tm over bbox via per-element predicate), and partial
// tgt_area (n==0 blocks only). No atomics: distinct output slots.
__global__ void __launch_bounds__(256)
fused_k(const float4* __restrict__ om, const float4* __restrict__ tm,
        const float* __restrict__ bboxes, float* __restrict__ ws) {
    __shared__ float smO[4], smI[4], smT[4];
    int bn = blockIdx.x / SPLITS;
    int s  = blockIdx.x % SPLITS;
    int b  = bn / N_;
    int n  = bn % N_;

    float4 bb = reinterpret_cast<const float4*>(bboxes)[bn];
    int x1 = (int)floorf(bb.x), y1 = (int)floorf(bb.y);
    int x2 = (int)floorf(bb.z), y2 = (int)floorf(bb.w);

    const float4* omp = om + (size_t)bn * (HW / 4) + (size_t)s * CHUNK4;
    const float4* tmp = tm + (size_t)b  * (HW / 4) + (size_t)s * CHUNK4;
    int fbase = s * CHUNK4 * 4;  // flat float index base within the image

    float accO = 0.0f, accI = 0.0f, accT = 0.0f;
    for (int i = threadIdx.x; i < CHUNK4; i += 256) {
        float4 o = omp[i];
        float4 t = tmp[i];
        accO += o.x * t.x + o.y * t.y + o.z * t.z + o.w * t.w;
        accT += t.x + t.y + t.z + t.w;
        int fi = fbase + i * 4;
        int r  = fi / W_;          // W_=400; float4 spans 4 cols of one row
        int c  = fi - r * W_;
        if (r >= y1 && r < y2) {
            float ix = (c     >= x1 && c     < x2) ? t.x : 0.0f;
            float iy = (c + 1 >= x1 && c + 1 < x2) ? t.y : 0.0f;
            float iz = (c + 2 >= x1 && c + 2 < x2) ? t.z : 0.0f;
            float iw = (c + 3 >= x1 && c + 3 < x2) ? t.w : 0.0f;
            accI += ix + iy + iz + iw;
        }
    }
    // 3 simultaneous wave reductions, then cross-wave via LDS
#pragma unroll
    for (int off = 32; off > 0; off >>= 1) {
        accO += __shfl_down(accO, off, 64);
        accI += __shfl_down(accI, off, 64);
        accT += __shfl_down(accT, off, 64);
    }
    int lane = threadIdx.x & 63, wid = threadIdx.x >> 6;
    if (lane == 0) { smO[wid] = accO; smI[wid] = accI; smT[wid] = accT; }
    __syncthreads();
    if (threadIdx.x == 0) {
        ws[blockIdx.x]         = smO[0] + smO[1] + smO[2] + smO[3];
        ws[OFF_I + blockIdx.x] = smI[0] + smI[1] + smI[2] + smI[3];
        if (n == 0)
            ws[OFF_T + b * SPLITS + s] = smT[0] + smT[1] + smT[2] + smT[3];
    }
}

__global__ void __launch_bounds__(256)
finalize_k(const float* __restrict__ bboxes, const float* __restrict__ ws,
           float* __restrict__ out) {
    int bn = threadIdx.x;
    if (bn >= BN) return;
    int b = bn / N_;
    float ov = 0.0f, inter = 0.0f, tgt = 0.0f;
#pragma unroll
    for (int s = 0; s < SPLITS; ++s) {
        ov    += ws[bn * SPLITS + s];
        inter += ws[OFF_I + bn * SPLITS + s];
        tgt   += ws[OFF_T + b * SPLITS + s];
    }
    float4 bb = reinterpret_cast<const float4*>(bboxes)[bn];
    int x1 = (int)floorf(bb.x), y1 = (int)floorf(bb.y);
    int x2 = (int)floorf(bb.z), y2 = (int)floorf(bb.w);
    float cr = (float)max(0, min(y2, H_) - max(y1, 0));
    float cc = (float)max(0, min(x2, W_) - max(x1, 0));
    float box_area = cr * cc;
    float iou = inter / (box_area + tgt - inter + 1e-8f);
    out[bn * 2 + 0] = ov;
    out[bn * 2 + 1] = iou;
}

extern "C" void kernel_launch(void* const* d_in, const int* in_sizes, int n_in,
                              void* d_out, int out_size, void* d_ws, size_t ws_size,
                              hipStream_t stream) {
    const float*  bboxes = (const float*)d_in[0];
    const float4* om     = (const float4*)d_in[1];
    const float4* tm     = (const float4*)d_in[2];
    float* out = (float*)d_out;
    float* ws  = (float*)d_ws;

    fused_k<<<BN * SPLITS, 256, 0, stream>>>(om, tm, bboxes, ws);
    finalize_k<<<1, 256, 0, stream>>>(bboxes, ws, out);
}